// Round 7
// baseline (347.430 us; speedup 1.0000x reference)
//
#include <hip/hip_runtime.h>
#include <stdint.h>

// Problem constants (fixed by the reference): x is (128,1,512,512) fp32, k=2048.
#define B        128
#define ROW_N    262144                 // 512*512 elements per row
#define SCAN_BPR 32                     // scan blocks per row
#define THREADS  256
#define F4_PER_TH 8                     // 8 float4 = 32 floats per thread
#define STASH    16                     // per-thread stash cap (mean 1.46, P(ovf)~4e-13)
#define SSTRIDE  17                     // LDS stride (odd -> conflict-free stores)

// Speculative exact pre-filter: keep ALL elements with |x| >= 2.0.
// For the fixed N(0,1) input: k-th |x| ~= 2.66; >=2.0 population ~11.9k +- 107
// per row. n >= K guarantees the exact top-k lies within the candidate set.
// Any violation (stash cap, row cap, n < K) flags the row -> exact fallback.
#define B0_BITS  0x40000000u  // bit pattern of 2.0f (abs-bits compare)
#define CAND_CAP 16384        // per-row candidate capacity (+41 sigma)
#define FKSHIFT  17           // 14-bit fine key for tie resolution
#define FB0      8192         // (B0_BITS >> FKSHIFT)
#define NFB      8192         // fine buckets [8192, 16384)
#define TIE_CAP  2048         // ties in one fine bucket (mean ~190)
#define THREADS_SS 512        // select_scatter block size
// fallback (normally never runs)
#define KSHIFT   19
#define NBUCKET  4096
#define FB_TIE_CAP 4096

// workspace layout (bytes)
#define OFF_CNT  0                         // per-row candidate counters (B u32)
#define OFF_OFL  512                       // per-row overflow flags (B u32)
#define OFF_FLG  1024                      // per-row fallback flag (B int)
#define OFF_CAND 4096                      // B * CAND_CAP * uint2 = 16 MiB
#define MEMSET_BYTES 1536

// ---- scan: read-only stream + branchless per-thread stash compaction --------
// No __syncthreads, no ballots in the hot loop, no branches per element.
// Loads are grouped in their own unroll block (nothing in the process loop can
// alias them, so the compiler can keep all 8 float4 in flight).
__global__ __launch_bounds__(THREADS) void scan_kernel(const float* __restrict__ x,
                                                       unsigned* __restrict__ cand_count,
                                                       unsigned* __restrict__ row_oflow,
                                                       uint2* __restrict__ cand) {
    __shared__ unsigned stash[2][THREADS * SSTRIDE];   // 2 x 17 KiB (idx, bits)
    const int t = threadIdx.x;
    const int lane = t & 63;
    const int row = blockIdx.y;
    const int f4base = blockIdx.x * (SCAN_BPR == 0 ? 0 : (ROW_N / 4 / SCAN_BPR)) + t;  // 2048 f4/block
    const float4* src = (const float4*)(x + (size_t)row * ROW_N);

    float4 v[F4_PER_TH];
#pragma unroll
    for (int u = 0; u < F4_PER_TH; ++u) v[u] = src[f4base + u * THREADS];

    const unsigned sbase = (unsigned)t * SSTRIDE;
    unsigned cnt = 0;   // true candidate count (may exceed STASH -> flagged)
#pragma unroll
    for (int u = 0; u < F4_PER_TH; ++u) {
        const unsigned ebase = (unsigned)((f4base + u * THREADS) * 4);
        const unsigned bb[4] = {__float_as_uint(v[u].x), __float_as_uint(v[u].y),
                                __float_as_uint(v[u].z), __float_as_uint(v[u].w)};
#pragma unroll
        for (int c = 0; c < 4; ++c) {
            const unsigned slot = sbase + (cnt & (STASH - 1));
            stash[0][slot] = ebase + (unsigned)c;       // unconditional store
            stash[1][slot] = bb[c];                     // (rare-path data race-free:
            cnt += ((bb[c] & 0x7FFFFFFFu) >= B0_BITS);  //  slot advances only on hit)
        }
    }

    // wave-level compaction: shfl prefix-sum + one global atomic per wave
    const unsigned stored = cnt < STASH ? cnt : STASH;
    unsigned pre = stored;
#pragma unroll
    for (int off = 1; off < 64; off <<= 1) {
        const unsigned pv = __shfl_up(pre, off);
        if (lane >= off) pre += pv;
    }
    const unsigned wtotal = __shfl(pre, 63);
    const unsigned excl = pre - stored;
    const bool anyOver = __ballot(cnt > STASH) != 0ull;
    unsigned base = 0;
    if (lane == 0) {
        base = atomicAdd(&cand_count[row], wtotal);
        if (anyOver) row_oflow[row] = 1u;
    }
    base = __shfl(base, 0);
    uint2* rcand = cand + (size_t)row * CAND_CAP;
    for (unsigned i = 0; i < stored; ++i) {
        const unsigned g = base + excl + i;
        if (g < CAND_CAP)
            rcand[g] = make_uint2(stash[0][sbase + i], stash[1][sbase + i]);
    }
}

// -- select+scatter fused: per row, hist over candidates only, exact top-k -----
__global__ __launch_bounds__(THREADS_SS) void select_scatter_kernel(
        const uint2* __restrict__ cand, const unsigned* __restrict__ cand_count,
        const unsigned* __restrict__ row_oflow, const int* __restrict__ topk,
        float* __restrict__ out, int* __restrict__ row_flag) {
    const int row = blockIdx.x;
    const int t = threadIdx.x;
    const unsigned K = (unsigned)(*topk);
    const unsigned n = cand_count[row];
    const unsigned of = row_oflow[row];

    __shared__ unsigned h[NFB];          // 32 KiB fine-bucket hist
    __shared__ unsigned tidx[TIE_CAP];   // 8 KiB
    __shared__ unsigned tbits[TIE_CAP];  // 8 KiB
    __shared__ unsigned partial[THREADS_SS];
    __shared__ unsigned excl[THREADS_SS];
    __shared__ unsigned tcnt;
    __shared__ int sb, sneed;

    if (n < K || n > (unsigned)CAND_CAP || of) {   // block-uniform
        if (t == 0) row_flag[row] = 1;
        return;
    }
    for (int i = t; i < NFB; i += THREADS_SS) h[i] = 0;
    if (t == 0) tcnt = 0;
    __syncthreads();

    const uint2* rc = cand + (size_t)row * CAND_CAP;
    for (unsigned i = (unsigned)t; i < n; i += THREADS_SS) {
        const uint2 e = rc[i];
        atomicAdd(&h[((e.y & 0x7FFFFFFFu) >> FKSHIFT) - FB0], 1u);
    }
    __syncthreads();

    // suffix scan from the top fine bucket
    const int PER = NFB / THREADS_SS;   // 16
    unsigned s = 0;
#pragma unroll
    for (int i = 0; i < PER; ++i) s += h[NFB - 1 - (t * PER + i)];
    partial[t] = s;
    __syncthreads();
    if (t == 0) {
        unsigned c = 0;
        for (int i = 0; i < THREADS_SS; ++i) { excl[i] = c; c += partial[i]; }
    }
    __syncthreads();
    unsigned cum = excl[t];
#pragma unroll
    for (int i = 0; i < PER; ++i) {
        const int brel = NFB - 1 - (t * PER + i);
        const unsigned c = h[brel];
        if (cum < K && cum + c >= K) {   // unique crossing
            sb = brel + FB0;
            sneed = (int)(K - cum);
        }
        cum += c;
    }
    __syncthreads();
    const int b = sb;
    const int need = sneed;
    if (h[b - FB0] > (unsigned)TIE_CAP) {   // block-uniform; before any writes
        if (t == 0) row_flag[row] = 1;
        return;
    }

    // scatter winners above the tie bucket; collect ties
    float* rout = out + (size_t)row * ROW_N;
    for (unsigned i = (unsigned)t; i < n; i += THREADS_SS) {
        const uint2 e = rc[i];
        const int fk = (int)((e.y & 0x7FFFFFFFu) >> FKSHIFT);
        if (fk > b) {
            rout[e.x] = __uint_as_float(e.y);
        } else if (fk == b) {
            const unsigned p = atomicAdd(&tcnt, 1u);
            tidx[p] = e.x; tbits[p] = e.y;   // p < TIE_CAP guaranteed (hist check)
        }
    }
    __syncthreads();

    // exact rank among ties: desc |x| bits, asc index (matches lax.top_k)
    const int c = (int)tcnt;
    for (int i = t; i < c; i += THREADS_SS) {
        const unsigned bits = tbits[i], idx = tidx[i];
        const uint64_t key = ((uint64_t)(bits & 0x7FFFFFFFu) << 32) | (uint64_t)(~idx);
        int rank = 0;
        for (int j = 0; j < c; ++j) {
            const uint64_t kj = ((uint64_t)(tbits[j] & 0x7FFFFFFFu) << 32) | (uint64_t)(~tidx[j]);
            rank += (kj > key) ? 1 : 0;
        }
        if (rank < need) rout[idx] = __uint_as_float(bits);
    }
}

// ---- fallback: self-contained exact solve for flagged rows (normally no-op) --
__global__ __launch_bounds__(THREADS) void fallback_kernel(const float* __restrict__ x,
                                                           float* __restrict__ out,
                                                           const int* __restrict__ topk,
                                                           const int* __restrict__ row_flag) {
    const int row = blockIdx.x;
    if (!row_flag[row]) return;
    const int t = threadIdx.x;
    const unsigned K = (unsigned)(*topk);
    const float4* xr = (const float4*)(x + (size_t)row * ROW_N);
    float* rout = out + (size_t)row * ROW_N;   // zeroed by the d_out memset

    __shared__ unsigned h[NBUCKET];          // 16 KiB coarse hist
    __shared__ unsigned tidx[FB_TIE_CAP];    // 16 KiB
    __shared__ unsigned tbits[FB_TIE_CAP];   // 16 KiB
    __shared__ unsigned partial[THREADS];
    __shared__ unsigned excl[THREADS];
    __shared__ unsigned tcnt;
    __shared__ int sb, sneed;
    for (int i = t; i < NBUCKET; i += THREADS) h[i] = 0;
    if (t == 0) tcnt = 0;
    __syncthreads();

    for (int i4 = t; i4 < ROW_N / 4; i4 += THREADS) {
        const float4 v = xr[i4];
        atomicAdd(&h[(__float_as_uint(v.x) & 0x7FFFFFFFu) >> KSHIFT], 1u);
        atomicAdd(&h[(__float_as_uint(v.y) & 0x7FFFFFFFu) >> KSHIFT], 1u);
        atomicAdd(&h[(__float_as_uint(v.z) & 0x7FFFFFFFu) >> KSHIFT], 1u);
        atomicAdd(&h[(__float_as_uint(v.w) & 0x7FFFFFFFu) >> KSHIFT], 1u);
    }
    __syncthreads();

    const int PER = NBUCKET / THREADS;   // 16
    unsigned s = 0;
#pragma unroll
    for (int i = 0; i < PER; ++i) s += h[NBUCKET - 1 - (t * PER + i)];
    partial[t] = s;
    __syncthreads();
    if (t == 0) {
        unsigned c = 0;
        for (int i = 0; i < THREADS; ++i) { excl[i] = c; c += partial[i]; }
    }
    __syncthreads();
    unsigned cum = excl[t];
#pragma unroll
    for (int i = 0; i < PER; ++i) {
        const int bucket = NBUCKET - 1 - (t * PER + i);
        const unsigned c = h[bucket];
        if (cum < K && cum + c >= K) { sb = bucket; sneed = (int)(K - cum); }
        cum += c;
    }
    __syncthreads();
    const int b = sb;
    const int need = sneed;

    for (int i4 = t; i4 < ROW_N / 4; i4 += THREADS) {
        const float4 v = xr[i4];
        const unsigned bits4[4] = {__float_as_uint(v.x), __float_as_uint(v.y),
                                   __float_as_uint(v.z), __float_as_uint(v.w)};
#pragma unroll
        for (int c = 0; c < 4; ++c) {
            const int key = (int)((bits4[c] & 0x7FFFFFFFu) >> KSHIFT);
            if (key > b) {
                rout[i4 * 4 + c] = __uint_as_float(bits4[c]);
            } else if (key == b) {
                const unsigned p = atomicAdd(&tcnt, 1u);
                if (p < FB_TIE_CAP) { tidx[p] = (unsigned)(i4 * 4 + c); tbits[p] = bits4[c]; }
            }
        }
    }
    __syncthreads();
    const int c = (int)(tcnt < (unsigned)FB_TIE_CAP ? tcnt : (unsigned)FB_TIE_CAP);
    for (int i = t; i < c; i += THREADS) {
        const unsigned bits = tbits[i], idx = tidx[i];
        const uint64_t key = ((uint64_t)(bits & 0x7FFFFFFFu) << 32) | (uint64_t)(~idx);
        int rank = 0;
        for (int j = 0; j < c; ++j) {
            const uint64_t kj = ((uint64_t)(tbits[j] & 0x7FFFFFFFu) << 32) | (uint64_t)(~tidx[j]);
            rank += (kj > key) ? 1 : 0;
        }
        if (rank < need) rout[idx] = __uint_as_float(bits);
    }
}

extern "C" void kernel_launch(void* const* d_in, const int* in_sizes, int n_in,
                              void* d_out, int out_size, void* d_ws, size_t ws_size,
                              hipStream_t stream) {
    const float* x = (const float*)d_in[0];
    const int* topk = (const int*)d_in[1];
    float* out = (float*)d_out;
    char* ws = (char*)d_ws;

    unsigned* cand_count = (unsigned*)(ws + OFF_CNT);
    unsigned* row_oflow  = (unsigned*)(ws + OFF_OFL);
    int* row_flag        = (int*)(ws + OFF_FLG);
    uint2* cand          = (uint2*)(ws + OFF_CAND);

    // zero counters + flags (ws is re-poisoned to 0xAA before each run), and
    // zero d_out via the rocclr fill path (5.5-6.5 TB/s vs ~1.5 in-kernel).
    hipMemsetAsync(ws, 0, MEMSET_BYTES, stream);
    hipMemsetAsync(out, 0, (size_t)out_size * sizeof(float), stream);

    dim3 gridS(SCAN_BPR, B);  // 32 x 128 = 4096 blocks
    scan_kernel<<<gridS, THREADS, 0, stream>>>(x, cand_count, row_oflow, cand);
    select_scatter_kernel<<<B, THREADS_SS, 0, stream>>>(cand, cand_count, row_oflow,
                                                        topk, out, row_flag);
    fallback_kernel<<<B, THREADS, 0, stream>>>(x, out, topk, row_flag);
}

// Round 8
// 343.544 us; speedup vs baseline: 1.0113x; 1.0113x over previous
//
#include <hip/hip_runtime.h>
#include <stdint.h>

// Problem constants (fixed by the reference): x is (128,1,512,512) fp32, k=2048.
#define B        128
#define ROW_N    262144                 // 512*512 elements per row
#define SCAN_BPR 32                     // scan blocks per row
#define THREADS  256
#define F4_PER_TH 8                     // 8 float4 = 32 floats per thread

// Speculative exact pre-filter: keep ALL elements with |x| >= 2.0.
// For the fixed N(0,1) input: k-th |x| ~= 2.66; >=2.0 population ~11.9k +- 107
// per row. n >= K guarantees the exact top-k lies within the candidate set.
// Any violation (row cap, n < K, tie cap) flags the row -> exact fallback.
#define B0_BITS  0x40000000u  // bit pattern of 2.0f (abs-bits compare)
#define CAND_CAP 16384        // per-row candidate capacity (+41 sigma)
#define FKSHIFT  17           // 14-bit fine key for tie resolution
#define FB0      8192         // (B0_BITS >> FKSHIFT)
#define NFB      8192         // fine buckets [8192, 16384)
#define TIE_CAP  2048         // ties in one fine bucket (mean ~190)
#define THREADS_SS 512        // select_scatter block size
// fallback (normally never runs)
#define KSHIFT   19
#define NBUCKET  4096
#define FB_TIE_CAP 4096

// workspace layout (bytes)
#define OFF_CNT  0                         // per-row candidate counters (B u32)
#define OFF_FLG  512                       // per-row fallback flag (B int)
#define OFF_CAND 4096                      // B * CAND_CAP * uint2 = 16 MiB
#define MEMSET_BYTES 1024

// ---- scan: pure-read stream. No LDS, no barriers, no per-element branches. ---
// Per thread: 8 coalesced float4 loads -> 32-bit predicate mask (3 VALU/elem)
// -> popc -> wave shfl-prefix -> ONE global atomic per wave -> predicated
// unrolled walk stores candidates to consecutive global slots (coalesced).
__global__ __launch_bounds__(THREADS) void scan_kernel(const float* __restrict__ x,
                                                       unsigned* __restrict__ cand_count,
                                                       uint2* __restrict__ cand) {
    const int t = threadIdx.x;
    const int lane = t & 63;
    const int row = blockIdx.y;
    const int f4base = blockIdx.x * (ROW_N / 4 / SCAN_BPR) + t;   // 2048 f4/block
    const float4* src = (const float4*)(x + (size_t)row * ROW_N);

    float4 v[F4_PER_TH];
#pragma unroll
    for (int u = 0; u < F4_PER_TH; ++u) v[u] = src[f4base + u * THREADS];

    // branchless predicate mask: bit (u*4+c) = (|v[u].c| >= 2.0)
    unsigned m = 0;
#pragma unroll
    for (int u = 0; u < F4_PER_TH; ++u) {
        const unsigned a0 = __float_as_uint(v[u].x) & 0x7FFFFFFFu;
        const unsigned a1 = __float_as_uint(v[u].y) & 0x7FFFFFFFu;
        const unsigned a2 = __float_as_uint(v[u].z) & 0x7FFFFFFFu;
        const unsigned a3 = __float_as_uint(v[u].w) & 0x7FFFFFFFu;
        m |= (a0 >= B0_BITS ? 1u : 0u) << (u * 4 + 0);
        m |= (a1 >= B0_BITS ? 1u : 0u) << (u * 4 + 1);
        m |= (a2 >= B0_BITS ? 1u : 0u) << (u * 4 + 2);
        m |= (a3 >= B0_BITS ? 1u : 0u) << (u * 4 + 3);
    }
    const unsigned cnt = (unsigned)__popc(m);

    // wave-level exclusive prefix sum of cnt
    unsigned pre = cnt;
#pragma unroll
    for (int off = 1; off < 64; off <<= 1) {
        const unsigned pv = __shfl_up(pre, off);
        if (lane >= off) pre += pv;
    }
    const unsigned wtotal = __shfl(pre, 63);
    const unsigned excl = pre - cnt;

    unsigned base = 0;
    if (lane == 0) base = atomicAdd(&cand_count[row], wtotal);  // 1 atomic/wave
    base = __shfl(base, 0);

    // predicated unrolled walk: lane's candidates -> consecutive global slots
    uint2* rcand = cand + (size_t)row * CAND_CAP;
    unsigned pos = base + excl;
#pragma unroll
    for (int u = 0; u < F4_PER_TH; ++u) {
        const float fv[4] = {v[u].x, v[u].y, v[u].z, v[u].w};
#pragma unroll
        for (int c = 0; c < 4; ++c) {
            if (m & (1u << (u * 4 + c))) {
                if (pos < CAND_CAP)
                    rcand[pos] = make_uint2((unsigned)((f4base + u * THREADS) * 4 + c),
                                            __float_as_uint(fv[c]));
                ++pos;
            }
        }
    }
}

// -- select+scatter fused: per row, hist over candidates only, exact top-k -----
__global__ __launch_bounds__(THREADS_SS) void select_scatter_kernel(
        const uint2* __restrict__ cand, const unsigned* __restrict__ cand_count,
        const int* __restrict__ topk, float* __restrict__ out,
        int* __restrict__ row_flag) {
    const int row = blockIdx.x;
    const int t = threadIdx.x;
    const unsigned K = (unsigned)(*topk);
    const unsigned n = cand_count[row];

    __shared__ unsigned h[NFB];          // 32 KiB fine-bucket hist
    __shared__ unsigned tidx[TIE_CAP];   // 8 KiB
    __shared__ unsigned tbits[TIE_CAP];  // 8 KiB
    __shared__ unsigned partial[THREADS_SS];
    __shared__ unsigned excl[THREADS_SS];
    __shared__ unsigned tcnt;
    __shared__ int sb, sneed;

    if (n < K || n > (unsigned)CAND_CAP) {   // block-uniform
        if (t == 0) row_flag[row] = 1;
        return;
    }
    for (int i = t; i < NFB; i += THREADS_SS) h[i] = 0;
    if (t == 0) tcnt = 0;
    __syncthreads();

    const uint2* rc = cand + (size_t)row * CAND_CAP;
    for (unsigned i = (unsigned)t; i < n; i += THREADS_SS) {
        const uint2 e = rc[i];
        atomicAdd(&h[((e.y & 0x7FFFFFFFu) >> FKSHIFT) - FB0], 1u);
    }
    __syncthreads();

    // suffix scan from the top fine bucket
    const int PER = NFB / THREADS_SS;   // 16
    unsigned s = 0;
#pragma unroll
    for (int i = 0; i < PER; ++i) s += h[NFB - 1 - (t * PER + i)];
    partial[t] = s;
    __syncthreads();
    if (t == 0) {
        unsigned c = 0;
        for (int i = 0; i < THREADS_SS; ++i) { excl[i] = c; c += partial[i]; }
    }
    __syncthreads();
    unsigned cum = excl[t];
#pragma unroll
    for (int i = 0; i < PER; ++i) {
        const int brel = NFB - 1 - (t * PER + i);
        const unsigned c = h[brel];
        if (cum < K && cum + c >= K) {   // unique crossing
            sb = brel + FB0;
            sneed = (int)(K - cum);
        }
        cum += c;
    }
    __syncthreads();
    const int b = sb;
    const int need = sneed;
    if (h[b - FB0] > (unsigned)TIE_CAP) {   // block-uniform; before any writes
        if (t == 0) row_flag[row] = 1;
        return;
    }

    // scatter winners above the tie bucket; collect ties
    float* rout = out + (size_t)row * ROW_N;
    for (unsigned i = (unsigned)t; i < n; i += THREADS_SS) {
        const uint2 e = rc[i];
        const int fk = (int)((e.y & 0x7FFFFFFFu) >> FKSHIFT);
        if (fk > b) {
            rout[e.x] = __uint_as_float(e.y);
        } else if (fk == b) {
            const unsigned p = atomicAdd(&tcnt, 1u);
            tidx[p] = e.x; tbits[p] = e.y;   // p < TIE_CAP guaranteed (hist check)
        }
    }
    __syncthreads();

    // exact rank among ties: desc |x| bits, asc index (matches lax.top_k)
    const int c = (int)tcnt;
    for (int i = t; i < c; i += THREADS_SS) {
        const unsigned bits = tbits[i], idx = tidx[i];
        const uint64_t key = ((uint64_t)(bits & 0x7FFFFFFFu) << 32) | (uint64_t)(~idx);
        int rank = 0;
        for (int j = 0; j < c; ++j) {
            const uint64_t kj = ((uint64_t)(tbits[j] & 0x7FFFFFFFu) << 32) | (uint64_t)(~tidx[j]);
            rank += (kj > key) ? 1 : 0;
        }
        if (rank < need) rout[idx] = __uint_as_float(bits);
    }
}

// ---- fallback: self-contained exact solve for flagged rows (normally no-op) --
__global__ __launch_bounds__(THREADS) void fallback_kernel(const float* __restrict__ x,
                                                           float* __restrict__ out,
                                                           const int* __restrict__ topk,
                                                           const int* __restrict__ row_flag) {
    const int row = blockIdx.x;
    if (!row_flag[row]) return;
    const int t = threadIdx.x;
    const unsigned K = (unsigned)(*topk);
    const float4* xr = (const float4*)(x + (size_t)row * ROW_N);
    float* rout = out + (size_t)row * ROW_N;   // zeroed by the d_out memset

    __shared__ unsigned h[NBUCKET];          // 16 KiB coarse hist
    __shared__ unsigned tidx[FB_TIE_CAP];    // 16 KiB
    __shared__ unsigned tbits[FB_TIE_CAP];   // 16 KiB
    __shared__ unsigned partial[THREADS];
    __shared__ unsigned excl[THREADS];
    __shared__ unsigned tcnt;
    __shared__ int sb, sneed;
    for (int i = t; i < NBUCKET; i += THREADS) h[i] = 0;
    if (t == 0) tcnt = 0;
    __syncthreads();

    for (int i4 = t; i4 < ROW_N / 4; i4 += THREADS) {
        const float4 v = xr[i4];
        atomicAdd(&h[(__float_as_uint(v.x) & 0x7FFFFFFFu) >> KSHIFT], 1u);
        atomicAdd(&h[(__float_as_uint(v.y) & 0x7FFFFFFFu) >> KSHIFT], 1u);
        atomicAdd(&h[(__float_as_uint(v.z) & 0x7FFFFFFFu) >> KSHIFT], 1u);
        atomicAdd(&h[(__float_as_uint(v.w) & 0x7FFFFFFFu) >> KSHIFT], 1u);
    }
    __syncthreads();

    const int PER = NBUCKET / THREADS;   // 16
    unsigned s = 0;
#pragma unroll
    for (int i = 0; i < PER; ++i) s += h[NBUCKET - 1 - (t * PER + i)];
    partial[t] = s;
    __syncthreads();
    if (t == 0) {
        unsigned c = 0;
        for (int i = 0; i < THREADS; ++i) { excl[i] = c; c += partial[i]; }
    }
    __syncthreads();
    unsigned cum = excl[t];
#pragma unroll
    for (int i = 0; i < PER; ++i) {
        const int bucket = NBUCKET - 1 - (t * PER + i);
        const unsigned c = h[bucket];
        if (cum < K && cum + c >= K) { sb = bucket; sneed = (int)(K - cum); }
        cum += c;
    }
    __syncthreads();
    const int b = sb;
    const int need = sneed;

    for (int i4 = t; i4 < ROW_N / 4; i4 += THREADS) {
        const float4 v = xr[i4];
        const unsigned bits4[4] = {__float_as_uint(v.x), __float_as_uint(v.y),
                                   __float_as_uint(v.z), __float_as_uint(v.w)};
#pragma unroll
        for (int c = 0; c < 4; ++c) {
            const int key = (int)((bits4[c] & 0x7FFFFFFFu) >> KSHIFT);
            if (key > b) {
                rout[i4 * 4 + c] = __uint_as_float(bits4[c]);
            } else if (key == b) {
                const unsigned p = atomicAdd(&tcnt, 1u);
                if (p < FB_TIE_CAP) { tidx[p] = (unsigned)(i4 * 4 + c); tbits[p] = bits4[c]; }
            }
        }
    }
    __syncthreads();
    const int c = (int)(tcnt < (unsigned)FB_TIE_CAP ? tcnt : (unsigned)FB_TIE_CAP);
    for (int i = t; i < c; i += THREADS) {
        const unsigned bits = tbits[i], idx = tidx[i];
        const uint64_t key = ((uint64_t)(bits & 0x7FFFFFFFu) << 32) | (uint64_t)(~idx);
        int rank = 0;
        for (int j = 0; j < c; ++j) {
            const uint64_t kj = ((uint64_t)(tbits[j] & 0x7FFFFFFFu) << 32) | (uint64_t)(~tidx[j]);
            rank += (kj > key) ? 1 : 0;
        }
        if (rank < need) rout[idx] = __uint_as_float(bits);
    }
}

extern "C" void kernel_launch(void* const* d_in, const int* in_sizes, int n_in,
                              void* d_out, int out_size, void* d_ws, size_t ws_size,
                              hipStream_t stream) {
    const float* x = (const float*)d_in[0];
    const int* topk = (const int*)d_in[1];
    float* out = (float*)d_out;
    char* ws = (char*)d_ws;

    unsigned* cand_count = (unsigned*)(ws + OFF_CNT);
    int* row_flag        = (int*)(ws + OFF_FLG);
    uint2* cand          = (uint2*)(ws + OFF_CAND);

    // counters first (scan needs them), then scan (reads x while L3 is warm),
    // then out-zeroing on the fast rocclr fill path (5.5-6.5 TB/s measured).
    hipMemsetAsync(ws, 0, MEMSET_BYTES, stream);
    dim3 gridS(SCAN_BPR, B);  // 32 x 128 = 4096 blocks
    scan_kernel<<<gridS, THREADS, 0, stream>>>(x, cand_count, cand);
    hipMemsetAsync(out, 0, (size_t)out_size * sizeof(float), stream);
    select_scatter_kernel<<<B, THREADS_SS, 0, stream>>>(cand, cand_count, topk,
                                                        out, row_flag);
    fallback_kernel<<<B, THREADS, 0, stream>>>(x, out, topk, row_flag);
}